// Round 3
// baseline (292.414 us; speedup 1.0000x reference)
//
#include <hip/hip_runtime.h>
#include <hip/hip_bf16.h>
#include <stdint.h>
#include <cmath>

// IDXST_IDCT on MI355X: y = S · x · C^T with
//   C[v,q] = cos(pi*q*(2v+1)/(2N)),  S[u,p] = sin(pi*p*(2u+1)/(2M))
// Butterfly halves GEMM FLOPs (dual E/O accumulators, fused epilogue).
// R9 (resubmit; prior run died to container-acquisition infra failure):
// counted-vmcnt schedule (T3+T4+T5). BM=128 x BN=256 x BK=64, 512 thr
// (8 waves, 2m x 4n, 64x64/wave), grid 16x16 = 256 blocks = 1/CU.
// The E/O parity pair is the LDS double buffer. Per K-step, 4 half-phases
// {8 ds_read_b128; lgkmcnt(0); 16 MFMA (setprio 1)}; staging uses raw
// s_barrier + s_waitcnt vmcnt(6) so the next parity's 6 global_load_lds
// stay in flight ACROSS barriers (never drained to 0 mid-loop) with two
// full phases of compute cover. Every inline waitcnt is followed by
// sched_barrier(0) (compiler hoist hazard, guide rule #18).
// XOR-swizzled LDS (verified zero bank conflicts), XCD-aware block swizzle.
// 3 dispatches total: prep, F1 (GEMM+bfly1+deint), F2 (GEMM+bfly2).

typedef __attribute__((ext_vector_type(4))) float f32x4;
typedef __attribute__((ext_vector_type(8))) unsigned short u16x8;
typedef __attribute__((ext_vector_type(8))) __bf16 bf16x8;

__device__ __forceinline__ unsigned short f2bf(float f) {
  union { float f; unsigned u; } v; v.f = f;
  unsigned u = v.u + 0x7fffu + ((v.u >> 16) & 1u);  // RNE
  return (unsigned short)(u >> 16);
}

// ---- gen device helper: half transform matrices [L/2 x L/2] bf16 ----
// Pe[i,j] = f(pi*(2j)(2i+1)/(2L)), Po[i,j] = f(pi*(2j+1)(2i+1)/(2L)).
// r tracked mod 4L (power of two -> exact in u32).
__device__ __forceinline__ void gen_half(int idx, u16x8* Pe, u16x8* Po,
                                         int isSin, int jshift, int jmask,
                                         unsigned mask4L, float sc) {
  int i = idx >> jshift;           // row
  int jb = (idx & jmask) * 8;      // first col
  unsigned tp = 2u * (unsigned)i + 1u;
  unsigned re = (2u * (unsigned)jb * tp) & mask4L;
  unsigned ro = (re + tp) & mask4L;
  unsigned step = (2u * tp) & mask4L;
  u16x8 pe, po;
#pragma unroll
  for (int t = 0; t < 8; t++) {
    float se_, ce_, so_, co_;
    __sincosf((float)re * sc, &se_, &ce_);
    __sincosf((float)ro * sc, &so_, &co_);
    pe[t] = f2bf(isSin ? se_ : ce_);
    po[t] = f2bf(isSin ? so_ : co_);
    re = (re + step) & mask4L;
    ro = (ro + step) & mask4L;
  }
  Pe[idx] = pe;
  Po[idx] = po;
}

// ---- single prep dispatch: convert+deint | gen Ce/Co | gen Se/So ----
__global__ void prep_kernel(const f32x4* __restrict__ x, u16x8* __restrict__ xe,
                            u16x8* __restrict__ xo, u16x8* __restrict__ Ce,
                            u16x8* __restrict__ Co, u16x8* __restrict__ Se,
                            u16x8* __restrict__ So, int nConvBlocks,
                            int nGenNBlocks, int jshiftN, int jmaskN,
                            unsigned mask4N, float scN, int jshiftM, int jmaskM,
                            unsigned mask4M, float scM) {
  int b = blockIdx.x;
  if (b < nConvBlocks) {
    int idx = b * 256 + threadIdx.x;
    f32x4 a = x[4 * idx], bb = x[4 * idx + 1], c = x[4 * idx + 2],
          d = x[4 * idx + 3];
    u16x8 e, o;
    e[0] = f2bf(a[0]);  o[0] = f2bf(a[1]);  e[1] = f2bf(a[2]);  o[1] = f2bf(a[3]);
    e[2] = f2bf(bb[0]); o[2] = f2bf(bb[1]); e[3] = f2bf(bb[2]); o[3] = f2bf(bb[3]);
    e[4] = f2bf(c[0]);  o[4] = f2bf(c[1]);  e[5] = f2bf(c[2]);  o[5] = f2bf(c[3]);
    e[6] = f2bf(d[0]);  o[6] = f2bf(d[1]);  e[7] = f2bf(d[2]);  o[7] = f2bf(d[3]);
    xe[idx] = e;
    xo[idx] = o;
  } else if (b < nConvBlocks + nGenNBlocks) {
    int idx = (b - nConvBlocks) * 256 + threadIdx.x;
    gen_half(idx, Ce, Co, 0, jshiftN, jmaskN, mask4N, scN);
  } else {
    int idx = (b - nConvBlocks - nGenNBlocks) * 256 + threadIdx.x;
    gen_half(idx, Se, So, 1, jshiftM, jmaskM, mask4M, scM);
  }
}

#define LGKM0()                                             \
  do {                                                      \
    asm volatile("s_waitcnt lgkmcnt(0)" ::: "memory");      \
    __builtin_amdgcn_sched_barrier(0);                      \
  } while (0)
#define VMCNT6()                                            \
  do {                                                      \
    asm volatile("s_waitcnt vmcnt(6)" ::: "memory");        \
    __builtin_amdgcn_sched_barrier(0);                      \
  } while (0)
#define VMCNT0()                                            \
  do {                                                      \
    asm volatile("s_waitcnt vmcnt(0)" ::: "memory");        \
    __builtin_amdgcn_sched_barrier(0);                      \
  } while (0)
#define BAR() __builtin_amdgcn_s_barrier()

// ---- fused dual bt-GEMM + butterfly epilogue, counted-vmcnt pipeline ----
// accE[m,n] = sum_k Ae[m,k]*Be[n,k]; accO likewise with Ao/Bo.
// BM=128, BN=256, BK=64, 512 threads (8 waves of 64x64; 2m x 4n).
// LDS: elem (row,col) at row*64 + ((col/8)^(row&7))*8 + col%8; staging lane l
// sources global col ((l&7)^(l>>3))*8 so dst stays wave-uniform-base+lane*16.
// STAGE==1 (m=v, n=p): (p&1?out1:out0)[v, p>>1] = E+O;
//                      [...][Lfull-1-v, p>>1]   = E-O   (bf16)
// STAGE==2 (m=u, n=v): y[u,v] = E+O; y[Lfull-1-u,v] = O-E  (fp32, out0)
template <int STAGE>
__global__ __launch_bounds__(512, 2) void fused_gemm_kernel(
    const unsigned short* __restrict__ Ae,
    const unsigned short* __restrict__ Ao,
    const unsigned short* __restrict__ Be,
    const unsigned short* __restrict__ Bo,
    unsigned short* __restrict__ out0, unsigned short* __restrict__ out1,
    int outStride, int K, int Lfull) {
  __shared__ unsigned short AsE[128 * 64];
  __shared__ unsigned short BsE[256 * 64];
  __shared__ unsigned short AsO[128 * 64];
  __shared__ unsigned short BsO[256 * 64];

  const int tid = threadIdx.x;

  // XCD-aware bijective block swizzle (nwg = 256, nwg%8 == 0).
  const int nwg = gridDim.x * gridDim.y;
  const int lin = blockIdx.y * gridDim.x + blockIdx.x;
  int swb = lin;
  if ((nwg & 7) == 0) swb = (lin & 7) * (nwg >> 3) + (lin >> 3);
  const int m0 = (swb / gridDim.x) * 128;
  const int n0 = (swb % gridDim.x) * 256;

  const int wave = tid >> 6;
  const int lane = tid & 63;
  const int wm = (wave >> 2) * 64;   // 2 m-waves
  const int wn = (wave & 3) * 64;    // 4 n-waves
  const int l16 = lane & 15;
  const int quad = lane >> 4;
  const int swz = (quad ^ (l16 & 7)) * 8;  // frag col swizzle, k-half 0

  // staging: each wave loads A-chunks {w, w+8} and B-chunks {w,+8,+16,+24};
  // chunk = 8 rows x 64 cols = 1 KB = one wave-wide global_load_lds.
  const int lrow = lane >> 3;                // row within chunk
  const int lsw = ((lane & 7) ^ lrow) * 8;   // swizzled source col (elems)

  auto stage = [&](const unsigned short* __restrict__ A,
                   const unsigned short* __restrict__ B, unsigned short* As,
                   unsigned short* Bs, int k0) {
    const unsigned short* Ap =
        A + (size_t)(m0 + 8 * wave + lrow) * K + lsw + k0;
    const unsigned short* Bp =
        B + (size_t)(n0 + 8 * wave + lrow) * K + lsw + k0;
    unsigned short* Adst = As + wave * 512;
    unsigned short* Bdst = Bs + wave * 512;
#define GLL(src, dst)                                                        \
  __builtin_amdgcn_global_load_lds(                                          \
      (const __attribute__((address_space(1))) void*)(src),                  \
      (__attribute__((address_space(3))) void*)(dst), 16, 0, 0)
    GLL(Ap, Adst);
    GLL(Ap + (size_t)64 * K, Adst + 4096);
    GLL(Bp, Bdst);
    GLL(Bp + (size_t)64 * K, Bdst + 4096);
    GLL(Bp + (size_t)128 * K, Bdst + 8192);
    GLL(Bp + (size_t)192 * K, Bdst + 12288);
#undef GLL
  };

  f32x4 accE[4][4], accO[4][4];
#pragma unroll
  for (int i = 0; i < 4; i++)
#pragma unroll
    for (int j = 0; j < 4; j++) {
      accE[i][j] = f32x4{0.f, 0.f, 0.f, 0.f};
      accO[i][j] = f32x4{0.f, 0.f, 0.f, 0.f};
    }

  // one half-phase: 8 ds_read_b128, wait own reads, 16 MFMA under setprio
  auto phase_h = [&](const unsigned short* As, const unsigned short* Bs,
                     int h, f32x4 (&acc)[4][4]) {
    const int so = swz ^ (h * 32);
    bf16x8 af[4], bfr[4];
#pragma unroll
    for (int i = 0; i < 4; i++)
      af[i] = *(const bf16x8*)(As + (wm + i * 16 + l16) * 64 + so);
#pragma unroll
    for (int j = 0; j < 4; j++)
      bfr[j] = *(const bf16x8*)(Bs + (wn + j * 16 + l16) * 64 + so);
    LGKM0();
    __builtin_amdgcn_s_setprio(1);
#pragma unroll
    for (int i = 0; i < 4; i++)
#pragma unroll
      for (int j = 0; j < 4; j++)
        acc[i][j] = __builtin_amdgcn_mfma_f32_16x16x32_bf16(
            af[i], bfr[j], acc[i][j], 0, 0, 0);
    __builtin_amdgcn_s_setprio(0);
  };

  // prologue: stage E(0) and O(0); wait only E(0) (own), then collect.
  stage(Ae, Be, AsE, BsE, 0);
  stage(Ao, Bo, AsO, BsO, 0);
  VMCNT6();
  BAR();

  // loop invariant at entry: E(k0) in LDS (collective), O(k0) in flight (6).
  for (int k0 = 0; k0 < K; k0 += 64) {
    const bool lastIt = (k0 + 64 >= K);

    phase_h(AsE, BsE, 0, accE);
    BAR();                       // alignment
    phase_h(AsE, BsE, 1, accE);
    BAR();                       // all waves past lgkm0 -> E buffers free
    if (!lastIt) {
      stage(Ae, Be, AsE, BsE, k0 + 64);  // 6 gloads; 12 in flight
      VMCNT6();                          // oldest 6 = O(k0) landed (own)
    } else {
      VMCNT0();
    }
    BAR();                       // O(k0) landed collectively

    phase_h(AsO, BsO, 0, accO);
    BAR();                       // alignment
    phase_h(AsO, BsO, 1, accO);
    BAR();                       // O buffers free
    if (!lastIt) {
      stage(Ao, Bo, AsO, BsO, k0 + 64);  // 6 gloads; 12 in flight
      VMCNT6();                          // oldest 6 = E(k0+64) landed (own)
    } else {
      VMCNT0();
    }
    BAR();                       // E(k0+64) landed collectively
  }

  // epilogue: D row = quad*4 + reg, col = lane&15; butterfly E/O in fp32
#pragma unroll
  for (int i = 0; i < 4; i++) {
#pragma unroll
    for (int j = 0; j < 4; j++) {
      int n = n0 + wn + j * 16 + l16;
      int mb = m0 + wm + i * 16 + quad * 4;
#pragma unroll
      for (int r = 0; r < 4; r++) {
        float e = accE[i][j][r];
        float o = accO[i][j][r];
        int m = mb + r;
        if (STAGE == 1) {
          unsigned short* mat = (n & 1) ? out1 : out0;
          int c = n >> 1;
          mat[(size_t)m * outStride + c] = f2bf(e + o);
          mat[(size_t)(Lfull - 1 - m) * outStride + c] = f2bf(e - o);
        } else {
          float* y = (float*)out0;
          y[(size_t)m * outStride + n] = e + o;
          y[(size_t)(Lfull - 1 - m) * outStride + n] = o - e;
        }
      }
    }
  }
}

extern "C" void kernel_launch(void* const* d_in, const int* in_sizes, int n_in,
                              void* d_out, int out_size, void* d_ws,
                              size_t ws_size, hipStream_t stream) {
  const float* x = (const float*)d_in[0];
  const int M = in_sizes[1] / 2;  // expkM is [M,2]
  const int N = in_sizes[2] / 2;  // expkN is [N,2]
  const size_t MN = (size_t)M * N;

  // workspace (u16 units), 3*MN u16 = 96 MB @4096:
  //  [0, MN/2)      xe  [M x N/2]
  //  [MN/2, MN)     xo  [M x N/2]
  //  [MN, 5MN/4)    Ce ; [5MN/4, 3MN/2) Co     [N/2 x N/2]
  //  [3MN/2, 7MN/4) Se ; [7MN/4, 2MN)   So     [M/2 x M/2]
  //  [2MN, 5MN/2)   tTe [N x M/2]
  //  [5MN/2, 3MN)   tTo [N x M/2]
  unsigned short* ws = (unsigned short*)d_ws;
  unsigned short* xe = ws;
  unsigned short* xo = ws + MN / 2;
  unsigned short* Ce = ws + MN;
  unsigned short* Co = ws + MN + MN / 4;
  unsigned short* Se = ws + MN * 3 / 2;
  unsigned short* So = ws + MN * 7 / 4;
  unsigned short* tTe = ws + MN * 2;
  unsigned short* tTo = ws + MN * 5 / 2;

  int shiftN = 0; while ((1 << shiftN) < N) shiftN++;
  int shiftM = 0; while ((1 << shiftM) < M) shiftM++;

  // 1: fused prep — convert+deint, gen Ce/Co, gen Se/So
  int nConvBlocks = (int)(MN / 16 / 256);
  int nGenNBlocks = (N / 2) * (N / 2) / 8 / 256;
  int nGenMBlocks = (M / 2) * (M / 2) / 8 / 256;
  prep_kernel<<<nConvBlocks + nGenNBlocks + nGenMBlocks, 256, 0, stream>>>(
      (const f32x4*)x, (u16x8*)xe, (u16x8*)xo, (u16x8*)Ce, (u16x8*)Co,
      (u16x8*)Se, (u16x8*)So, nConvBlocks, nGenNBlocks, shiftN - 4,
      (N / 16) - 1, (unsigned)(4 * N - 1),
      (float)(3.14159265358979323846 / (2.0 * N)), shiftM - 4, (M / 16) - 1,
      (unsigned)(4 * M - 1), (float)(3.14159265358979323846 / (2.0 * M)));

  // 2: F1 — E/O GEMMs (K=N/2) + v-butterfly + p-parity deint -> tTe/tTo
  //    grid: x over p (M/256), y over v' ((N/2)/128); 512 threads
  fused_gemm_kernel<1><<<dim3(M / 256, (N / 2) / 128), 512, 0, stream>>>(
      Ce, Co, xe, xo, tTe, tTo, M / 2, N / 2, N);

  // 3: F2 — E/O GEMMs (K=M/2) + u-butterfly -> y fp32
  //    grid: x over v (N/256), y over u' ((M/2)/128); 512 threads
  fused_gemm_kernel<2><<<dim3(N / 256, (M / 2) / 128), 512, 0, stream>>>(
      Se, So, tTe, tTo, (unsigned short*)d_out, nullptr, N, M / 2, M);
}

// Round 4
// 266.647 us; speedup vs baseline: 1.0966x; 1.0966x over previous
//
#include <hip/hip_runtime.h>
#include <hip/hip_bf16.h>
#include <stdint.h>
#include <cmath>

// IDXST_IDCT on MI355X: y = S · x · C^T with
//   C[v,q] = cos(pi*q*(2v+1)/(2N)),  S[u,p] = sin(pi*p*(2u+1)/(2M))
// Butterfly halves GEMM FLOPs (dual E/O accumulators, fused epilogue).
// R10: R7 geometry (BM=BN=128, BK=64, 256 thr / 4 waves, 2 blocks/CU ->
// cross-block TLP, which R8/R9's 1-block/CU lockstep killed) + counted
// waits (no mid-loop vmcnt(0)/lgkmcnt-pinning; R9's mistake was drain-
// style scheduling in a single barrier group). Per iter: stage O(k),
// vmcnt(8) retires E(k) only; read all 16 E-frags, lgkm(8) -> 16 MFMA
// (setprio) -> lgkm(0) -> 16 MFMA; bar; stage E(k+64), vmcnt(8); bar;
// same for O. E/O parity pair is the LDS double buffer.
// XOR-swizzled LDS (verified zero bank conflicts), XCD-aware block swizzle.
// 3 dispatches total: prep, F1 (GEMM+bfly1+deint), F2 (GEMM+bfly2).

typedef __attribute__((ext_vector_type(4))) float f32x4;
typedef __attribute__((ext_vector_type(8))) unsigned short u16x8;
typedef __attribute__((ext_vector_type(8))) __bf16 bf16x8;

__device__ __forceinline__ unsigned short f2bf(float f) {
  union { float f; unsigned u; } v; v.f = f;
  unsigned u = v.u + 0x7fffu + ((v.u >> 16) & 1u);  // RNE
  return (unsigned short)(u >> 16);
}

// ---- gen device helper: half transform matrices [L/2 x L/2] bf16 ----
// Pe[i,j] = f(pi*(2j)(2i+1)/(2L)), Po[i,j] = f(pi*(2j+1)(2i+1)/(2L)).
// r tracked mod 4L (power of two -> exact in u32).
__device__ __forceinline__ void gen_half(int idx, u16x8* Pe, u16x8* Po,
                                         int isSin, int jshift, int jmask,
                                         unsigned mask4L, float sc) {
  int i = idx >> jshift;           // row
  int jb = (idx & jmask) * 8;      // first col
  unsigned tp = 2u * (unsigned)i + 1u;
  unsigned re = (2u * (unsigned)jb * tp) & mask4L;
  unsigned ro = (re + tp) & mask4L;
  unsigned step = (2u * tp) & mask4L;
  u16x8 pe, po;
#pragma unroll
  for (int t = 0; t < 8; t++) {
    float se_, ce_, so_, co_;
    __sincosf((float)re * sc, &se_, &ce_);
    __sincosf((float)ro * sc, &so_, &co_);
    pe[t] = f2bf(isSin ? se_ : ce_);
    po[t] = f2bf(isSin ? so_ : co_);
    re = (re + step) & mask4L;
    ro = (ro + step) & mask4L;
  }
  Pe[idx] = pe;
  Po[idx] = po;
}

// ---- single prep dispatch: convert+deint | gen Ce/Co | gen Se/So ----
__global__ void prep_kernel(const f32x4* __restrict__ x, u16x8* __restrict__ xe,
                            u16x8* __restrict__ xo, u16x8* __restrict__ Ce,
                            u16x8* __restrict__ Co, u16x8* __restrict__ Se,
                            u16x8* __restrict__ So, int nConvBlocks,
                            int nGenNBlocks, int jshiftN, int jmaskN,
                            unsigned mask4N, float scN, int jshiftM, int jmaskM,
                            unsigned mask4M, float scM) {
  int b = blockIdx.x;
  if (b < nConvBlocks) {
    int idx = b * 256 + threadIdx.x;
    f32x4 a = x[4 * idx], bb = x[4 * idx + 1], c = x[4 * idx + 2],
          d = x[4 * idx + 3];
    u16x8 e, o;
    e[0] = f2bf(a[0]);  o[0] = f2bf(a[1]);  e[1] = f2bf(a[2]);  o[1] = f2bf(a[3]);
    e[2] = f2bf(bb[0]); o[2] = f2bf(bb[1]); e[3] = f2bf(bb[2]); o[3] = f2bf(bb[3]);
    e[4] = f2bf(c[0]);  o[4] = f2bf(c[1]);  e[5] = f2bf(c[2]);  o[5] = f2bf(c[3]);
    e[6] = f2bf(d[0]);  o[6] = f2bf(d[1]);  e[7] = f2bf(d[2]);  o[7] = f2bf(d[3]);
    xe[idx] = e;
    xo[idx] = o;
  } else if (b < nConvBlocks + nGenNBlocks) {
    int idx = (b - nConvBlocks) * 256 + threadIdx.x;
    gen_half(idx, Ce, Co, 0, jshiftN, jmaskN, mask4N, scN);
  } else {
    int idx = (b - nConvBlocks - nGenNBlocks) * 256 + threadIdx.x;
    gen_half(idx, Se, So, 1, jshiftM, jmaskM, mask4M, scM);
  }
}

#define LGKM8()                                             \
  do {                                                      \
    asm volatile("s_waitcnt lgkmcnt(8)" ::: "memory");      \
    __builtin_amdgcn_sched_barrier(0);                      \
  } while (0)
#define LGKM0()                                             \
  do {                                                      \
    asm volatile("s_waitcnt lgkmcnt(0)" ::: "memory");      \
    __builtin_amdgcn_sched_barrier(0);                      \
  } while (0)
#define VMCNT8()                                            \
  do {                                                      \
    asm volatile("s_waitcnt vmcnt(8)" ::: "memory");        \
    __builtin_amdgcn_sched_barrier(0);                      \
  } while (0)
#define VMCNT0()                                            \
  do {                                                      \
    asm volatile("s_waitcnt vmcnt(0)" ::: "memory");        \
    __builtin_amdgcn_sched_barrier(0);                      \
  } while (0)
#define BAR() __builtin_amdgcn_s_barrier()

// ---- fused dual bt-GEMM + butterfly epilogue, counted-wait pipeline ----
// accE[m,n] = sum_k Ae[m,k]*Be[n,k]; accO likewise with Ao/Bo.
// BM=BN=128, BK=64, 256 threads (4 waves of 64x64; 2m x 2n), 2 blocks/CU.
// LDS: elem (row,col) at row*64 + ((col/8)^(row&7))*8 + col%8; staging lane l
// sources global col ((l&7)^(l>>3))*8 so dst stays wave-uniform-base+lane*16.
// STAGE==1 (m=v, n=p): (p&1?out1:out0)[v, p>>1] = E+O;
//                      [...][Lfull-1-v, p>>1]   = E-O   (bf16)
// STAGE==2 (m=u, n=v): y[u,v] = E+O; y[Lfull-1-u,v] = O-E  (fp32, out0)
template <int STAGE>
__global__ __launch_bounds__(256, 2) void fused_gemm_kernel(
    const unsigned short* __restrict__ Ae,
    const unsigned short* __restrict__ Ao,
    const unsigned short* __restrict__ Be,
    const unsigned short* __restrict__ Bo,
    unsigned short* __restrict__ out0, unsigned short* __restrict__ out1,
    int outStride, int K, int Lfull) {
  __shared__ unsigned short AsE[128 * 64];
  __shared__ unsigned short BsE[128 * 64];
  __shared__ unsigned short AsO[128 * 64];
  __shared__ unsigned short BsO[128 * 64];

  const int tid = threadIdx.x;

  // XCD-aware bijective block swizzle (nwg = 512, nwg%8 == 0).
  const int nwg = gridDim.x * gridDim.y;
  const int lin = blockIdx.y * gridDim.x + blockIdx.x;
  int swb = lin;
  if ((nwg & 7) == 0) swb = (lin & 7) * (nwg >> 3) + (lin >> 3);
  const int m0 = (swb / gridDim.x) * 128;
  const int n0 = (swb % gridDim.x) * 128;

  const int wave = tid >> 6;
  const int lane = tid & 63;
  const int wm = (wave & 1) * 64;   // 2 m-waves
  const int wn = (wave >> 1) * 64;  // 2 n-waves
  const int l16 = lane & 15;
  const int quad = lane >> 4;
  const int swz = (quad ^ (l16 & 7)) * 8;  // frag col swizzle, k-half 0

  // staging: chunk = 8 rows x 64 cols = 1 KB = one wave-wide global_load_lds.
  // Each wave loads A-chunks {wave+4t} and B-chunks {wave+4t}, t=0..3.
  const int lrow = lane >> 3;                // row within chunk
  const int lsw = ((lane & 7) ^ lrow) * 8;   // swizzled source col (elems)

  auto stageP = [&](const unsigned short* __restrict__ A,
                    const unsigned short* __restrict__ B, unsigned short* As,
                    unsigned short* Bs, int k0) {
#define GLL(src, dst)                                                        \
  __builtin_amdgcn_global_load_lds(                                          \
      (const __attribute__((address_space(1))) void*)(src),                  \
      (__attribute__((address_space(3))) void*)(dst), 16, 0, 0)
#pragma unroll
    for (int t = 0; t < 4; t++) {
      int ch = wave + 4 * t;
      GLL(A + (size_t)(m0 + 8 * ch + lrow) * K + lsw + k0, As + ch * 512);
      GLL(B + (size_t)(n0 + 8 * ch + lrow) * K + lsw + k0, Bs + ch * 512);
    }
#undef GLL
  };

  f32x4 accE[4][4], accO[4][4];
#pragma unroll
  for (int i = 0; i < 4; i++)
#pragma unroll
    for (int j = 0; j < 4; j++) {
      accE[i][j] = f32x4{0.f, 0.f, 0.f, 0.f};
      accO[i][j] = f32x4{0.f, 0.f, 0.f, 0.f};
    }

  // one parity: read all 16 frags, counted-lgkm, 2x16 MFMA under setprio
  auto parity = [&](const unsigned short* As, const unsigned short* Bs,
                    f32x4 (&acc)[4][4]) {
    const int so0 = swz;
    const int so1 = swz ^ 32;
    bf16x8 a0[4], b0[4], a1[4], b1[4];
#pragma unroll
    for (int i = 0; i < 4; i++)
      a0[i] = *(const bf16x8*)(As + (wm + i * 16 + l16) * 64 + so0);
#pragma unroll
    for (int j = 0; j < 4; j++)
      b0[j] = *(const bf16x8*)(Bs + (wn + j * 16 + l16) * 64 + so0);
#pragma unroll
    for (int i = 0; i < 4; i++)
      a1[i] = *(const bf16x8*)(As + (wm + i * 16 + l16) * 64 + so1);
#pragma unroll
    for (int j = 0; j < 4; j++)
      b1[j] = *(const bf16x8*)(Bs + (wn + j * 16 + l16) * 64 + so1);
    LGKM8();  // oldest 8 = h0 frags landed
    __builtin_amdgcn_s_setprio(1);
#pragma unroll
    for (int i = 0; i < 4; i++)
#pragma unroll
      for (int j = 0; j < 4; j++)
        acc[i][j] = __builtin_amdgcn_mfma_f32_16x16x32_bf16(
            a0[i], b0[j], acc[i][j], 0, 0, 0);
    __builtin_amdgcn_s_setprio(0);
    LGKM0();  // h1 frags landed
    __builtin_amdgcn_s_setprio(1);
#pragma unroll
    for (int i = 0; i < 4; i++)
#pragma unroll
      for (int j = 0; j < 4; j++)
        acc[i][j] = __builtin_amdgcn_mfma_f32_16x16x32_bf16(
            a1[i], b1[j], acc[i][j], 0, 0, 0);
    __builtin_amdgcn_s_setprio(0);
  };

  // prologue: E(0) in flight (8/wave)
  stageP(Ae, Be, AsE, BsE, 0);

  // loop invariant at entry: E(k0) in flight (8/wave), O-buffers free.
  for (int k0 = 0; k0 < K; k0 += 64) {
    const bool lastIt = (k0 + 64 >= K);

    stageP(Ao, Bo, AsO, BsO, k0);  // 8 loads; 16 in flight
    VMCNT8();                      // oldest 8 = E(k0) landed (own)
    BAR();                         // E(k0) landed collectively
    parity(AsE, BsE, accE);
    BAR();                         // all waves' E reads done -> E bufs free

    if (!lastIt) {
      stageP(Ae, Be, AsE, BsE, k0 + 64);  // 8 loads; 16 in flight
      VMCNT8();                           // oldest 8 = O(k0) landed (own)
    } else {
      VMCNT0();                           // drain O(k0)
    }
    BAR();                         // O(k0) landed collectively
    parity(AsO, BsO, accO);
    BAR();                         // all waves' O reads done -> O bufs free
  }

  // epilogue: D row = quad*4 + reg, col = lane&15; butterfly E/O in fp32
#pragma unroll
  for (int i = 0; i < 4; i++) {
#pragma unroll
    for (int j = 0; j < 4; j++) {
      int n = n0 + wn + j * 16 + l16;
      int mb = m0 + wm + i * 16 + quad * 4;
#pragma unroll
      for (int r = 0; r < 4; r++) {
        float e = accE[i][j][r];
        float o = accO[i][j][r];
        int m = mb + r;
        if (STAGE == 1) {
          unsigned short* mat = (n & 1) ? out1 : out0;
          int c = n >> 1;
          mat[(size_t)m * outStride + c] = f2bf(e + o);
          mat[(size_t)(Lfull - 1 - m) * outStride + c] = f2bf(e - o);
        } else {
          float* y = (float*)out0;
          y[(size_t)m * outStride + n] = e + o;
          y[(size_t)(Lfull - 1 - m) * outStride + n] = o - e;
        }
      }
    }
  }
}

extern "C" void kernel_launch(void* const* d_in, const int* in_sizes, int n_in,
                              void* d_out, int out_size, void* d_ws,
                              size_t ws_size, hipStream_t stream) {
  const float* x = (const float*)d_in[0];
  const int M = in_sizes[1] / 2;  // expkM is [M,2]
  const int N = in_sizes[2] / 2;  // expkN is [N,2]
  const size_t MN = (size_t)M * N;

  // workspace (u16 units), 3*MN u16 = 96 MB @4096:
  //  [0, MN/2)      xe  [M x N/2]
  //  [MN/2, MN)     xo  [M x N/2]
  //  [MN, 5MN/4)    Ce ; [5MN/4, 3MN/2) Co     [N/2 x N/2]
  //  [3MN/2, 7MN/4) Se ; [7MN/4, 2MN)   So     [M/2 x M/2]
  //  [2MN, 5MN/2)   tTe [N x M/2]
  //  [5MN/2, 3MN)   tTo [N x M/2]
  unsigned short* ws = (unsigned short*)d_ws;
  unsigned short* xe = ws;
  unsigned short* xo = ws + MN / 2;
  unsigned short* Ce = ws + MN;
  unsigned short* Co = ws + MN + MN / 4;
  unsigned short* Se = ws + MN * 3 / 2;
  unsigned short* So = ws + MN * 7 / 4;
  unsigned short* tTe = ws + MN * 2;
  unsigned short* tTo = ws + MN * 5 / 2;

  int shiftN = 0; while ((1 << shiftN) < N) shiftN++;
  int shiftM = 0; while ((1 << shiftM) < M) shiftM++;

  // 1: fused prep — convert+deint, gen Ce/Co, gen Se/So
  int nConvBlocks = (int)(MN / 16 / 256);
  int nGenNBlocks = (N / 2) * (N / 2) / 8 / 256;
  int nGenMBlocks = (M / 2) * (M / 2) / 8 / 256;
  prep_kernel<<<nConvBlocks + nGenNBlocks + nGenMBlocks, 256, 0, stream>>>(
      (const f32x4*)x, (u16x8*)xe, (u16x8*)xo, (u16x8*)Ce, (u16x8*)Co,
      (u16x8*)Se, (u16x8*)So, nConvBlocks, nGenNBlocks, shiftN - 4,
      (N / 16) - 1, (unsigned)(4 * N - 1),
      (float)(3.14159265358979323846 / (2.0 * N)), shiftM - 4, (M / 16) - 1,
      (unsigned)(4 * M - 1), (float)(3.14159265358979323846 / (2.0 * M)));

  // 2: F1 — E/O GEMMs (K=N/2) + v-butterfly + p-parity deint -> tTe/tTo
  //    grid: x over p (M/128), y over v' ((N/2)/128); 256 threads
  fused_gemm_kernel<1><<<dim3(M / 128, (N / 2) / 128), 256, 0, stream>>>(
      Ce, Co, xe, xo, tTe, tTo, M / 2, N / 2, N);

  // 3: F2 — E/O GEMMs (K=M/2) + u-butterfly -> y fp32
  //    grid: x over v (N/128), y over u' ((M/2)/128); 256 threads
  fused_gemm_kernel<2><<<dim3(N / 128, (M / 2) / 128), 256, 0, stream>>>(
      Se, So, tTe, tTo, (unsigned short*)d_out, nullptr, N, M / 2, M);
}